// Round 4
// baseline (162.996 us; speedup 1.0000x reference)
//
#include <hip/hip_runtime.h>

#define CHN 96
#define IMG_H 256
#define IMG_W 256
#define STRIP 64          // rows per wave
#define WPB 8             // waves per block
#define GRP 8             // rows per pipelined group
#define NG (STRIP / GRP)  // 8 groups per strip

typedef float vfloat4 __attribute__((ext_vector_type(4)));

struct Row { float l, x, y, z, w, r; };

__device__ __forceinline__ Row mkrow(vfloat4 v, int lane) {
    Row r;
    r.x = v.x; r.y = v.y; r.z = v.z; r.w = v.w;
    r.l = __shfl_up(v.w, 1);
    r.r = __shfl_down(v.x, 1);
    if (lane == 0)  r.l = 0.f;   // x = -1 zero pad
    if (lane == 63) r.r = 0.f;   // x = 256 zero pad
    return r;
}

__device__ __forceinline__ vfloat4 ldrow(const float* xp, int yy, int col) {
    // yy >= 0 guaranteed by callers; zero-fill past the bottom edge.
    // Regular (cached) load: boundary rows are read by two waves -> L2 hit.
    if (yy < IMG_H)
        return *(const vfloat4*)(xp + (size_t)yy * IMG_W + col);
    return (vfloat4){0.f, 0.f, 0.f, 0.f};
}

__device__ __forceinline__ void ldgroup(vfloat4* buf, const float* xp,
                                        int y0, int col) {
    #pragma unroll
    for (int j = 0; j < GRP; ++j) buf[j] = ldrow(xp, y0 + j, col);
}

__device__ __forceinline__ vfloat4 stencil(const Row& a, const Row& b, const Row& c,
                                           float w0, float w1, float w2,
                                           float w3, float w4, float w5,
                                           float w6, float w7, float w8) {
    vfloat4 o;
    o.x = w0*a.l + w1*a.x + w2*a.y
        + w3*b.l + w4*b.x + w5*b.y
        + w6*c.l + w7*c.x + w8*c.y;
    o.y = w0*a.x + w1*a.y + w2*a.z
        + w3*b.x + w4*b.y + w5*b.z
        + w6*c.x + w7*c.y + w8*c.z;
    o.z = w0*a.y + w1*a.z + w2*a.w
        + w3*b.y + w4*b.z + w5*b.w
        + w6*c.y + w7*c.z + w8*c.w;
    o.w = w0*a.z + w1*a.w + w2*a.r
        + w3*b.z + w4*b.w + w5*b.r
        + w6*c.z + w7*c.w + w8*c.r;
    return o;
}

__device__ __forceinline__ void compute_group(const vfloat4* buf,
                                              Row& prev, Row& cur,
                                              float* op, int y, int col, int lane,
                                              float w0, float w1, float w2,
                                              float w3, float w4, float w5,
                                              float w6, float w7, float w8) {
    #pragma unroll
    for (int j = 0; j < GRP; ++j) {
        Row n = mkrow(buf[j], lane);             // input row y+j+1
        vfloat4 o = stencil(prev, cur, n, w0,w1,w2,w3,w4,w5,w6,w7,w8);
        __builtin_nontemporal_store(
            o, (vfloat4*)(op + (size_t)(y + j) * IMG_W + col));
        prev = cur;
        cur  = n;
    }
}

__global__ __launch_bounds__(WPB * 64)
void sharpen3x3_pp(const float* __restrict__ x,
                   const float* __restrict__ kern,
                   float* __restrict__ out)
{
    const int lane = threadIdx.x & 63;
    const int wave = threadIdx.x >> 6;

    const int strip_id = blockIdx.x * WPB + wave;            // 0..6143
    const int spp      = IMG_H / STRIP;                      // 4 strips per plane
    const int plane    = strip_id / spp;                     // n*CHN + c
    const int sy       = (strip_id % spp) * STRIP;           // first output row
    const int c        = plane % CHN;

    // diagonal 3x3 block of the dense (C,C,3,3) kernel
    const float* kw = kern + ((size_t)c * CHN + c) * 9;
    const float w0 = kw[0], w1 = kw[1], w2 = kw[2];
    const float w3 = kw[3], w4 = kw[4], w5 = kw[5];
    const float w6 = kw[6], w7 = kw[7], w8 = kw[8];

    const float* xp = x   + (size_t)plane * IMG_H * IMG_W;
    float*       op = out + (size_t)plane * IMG_H * IMG_W;

    const int col = 4 * lane;

    // prime: group 0 input rows sy+1 .. sy+GRP
    vfloat4 A[GRP], B[GRP];
    ldgroup(A, xp, sy + 1, col);

    Row prev, cur;
    if (sy == 0) {
        prev = Row{0.f, 0.f, 0.f, 0.f, 0.f, 0.f};
    } else {
        prev = mkrow(*(const vfloat4*)(xp + (size_t)(sy - 1) * IMG_W + col), lane);
    }
    cur = mkrow(*(const vfloat4*)(xp + (size_t)sy * IMG_W + col), lane);

    #pragma unroll 1
    for (int g = 0; g < NG; g += 2) {
        const int y = sy + g * GRP;

        // prefetch group g+1 while computing group g (no buffer copy, no drain)
        ldgroup(B, xp, y + GRP + 1, col);
        compute_group(A, prev, cur, op, y, col, lane,
                      w0,w1,w2,w3,w4,w5,w6,w7,w8);

        // prefetch group g+2 while computing group g+1
        if (g + 2 < NG)
            ldgroup(A, xp, y + 2 * GRP + 1, col);
        compute_group(B, prev, cur, op, y + GRP, col, lane,
                      w0,w1,w2,w3,w4,w5,w6,w7,w8);
    }
}

extern "C" void kernel_launch(void* const* d_in, const int* in_sizes, int n_in,
                              void* d_out, int out_size, void* d_ws, size_t ws_size,
                              hipStream_t stream) {
    const float* x    = (const float*)d_in[0];
    const float* kern = (const float*)d_in[1];
    float* out        = (float*)d_out;

    const int n_strips = 16 * CHN * (IMG_H / STRIP);   // 6144 waves
    const int grid     = n_strips / WPB;               // 768 blocks

    hipLaunchKernelGGL(sharpen3x3_pp, dim3(grid), dim3(WPB * 64),
                       0, stream, x, kern, out);
}

// Round 5
// 162.571 us; speedup vs baseline: 1.0026x; 1.0026x over previous
//
#include <hip/hip_runtime.h>

#define CHN 96
#define IMG_H 256
#define IMG_W 256
#define STRIP 64          // rows per wave
#define WPB 8             // waves per block (512 threads)
#define GRP 4             // rows per pipelined group (small: VGPR diet)
#define NG (STRIP / GRP)  // 16 groups per strip

typedef float vfloat4 __attribute__((ext_vector_type(4)));

__device__ __forceinline__ vfloat4 ldrow(const float* xp, int yy, int col) {
    // yy >= 0 guaranteed by callers; zero-fill past the bottom edge (uniform branch).
    if (yy < IMG_H)
        return __builtin_nontemporal_load(
            (const vfloat4*)(xp + (size_t)yy * IMG_W + col));
    return (vfloat4){0.f, 0.f, 0.f, 0.f};
}

// Horizontal 3-tap sum for each of the lane's 4 pixels (zero pad at x=-1/x=256).
__device__ __forceinline__ vfloat4 hsum3(vfloat4 v, int lane) {
    float l = __shfl_up(v.w, 1);
    float r = __shfl_down(v.x, 1);
    if (lane == 0)  l = 0.f;
    if (lane == 63) r = 0.f;
    float t1 = v.x + v.y;
    float t2 = v.z + v.w;
    vfloat4 h;
    h.x = l  + t1;
    h.y = t1 + v.z;
    h.z = v.y + t2;
    h.w = t2 + r;
    return h;
}

// out_row(y) = wn * (hsum(y-1) + hsum(y) + hsum(y+1)) + (w_center - wn) * x(y)
__device__ __forceinline__ void compute_group(const vfloat4* buf,
                                              vfloat4& hprev, vfloat4& hcur,
                                              vfloat4& ccur,
                                              float wn, float wd,
                                              float* op, int y, int col, int lane) {
    #pragma unroll
    for (int j = 0; j < GRP; ++j) {
        vfloat4 hn = hsum3(buf[j], lane);        // input row y+j+1
        vfloat4 s  = hprev + hcur + hn;          // 3x3 box sum
        vfloat4 o  = s * wn + ccur * wd;
        __builtin_nontemporal_store(
            o, (vfloat4*)(op + (size_t)(y + j) * IMG_W + col));
        hprev = hcur;
        hcur  = hn;
        ccur  = buf[j];
    }
}

__global__ __launch_bounds__(WPB * 64, 6)   // cap VGPR for 6 waves/SIMD: all 6144 waves co-resident
void sharpen3x3_lean(const float* __restrict__ x,
                     const float* __restrict__ kern,
                     float* __restrict__ out)
{
    const int lane = threadIdx.x & 63;
    const int wave = threadIdx.x >> 6;

    const int strip_id = blockIdx.x * WPB + wave;            // 0..6143
    const int spp      = IMG_H / STRIP;                      // 4 strips per plane
    const int plane    = strip_id / spp;                     // n*CHN + c
    const int sy       = (strip_id % spp) * STRIP;           // first output row
    const int c        = plane % CHN;

    // Diagonal 3x3 block of the dense (C,C,3,3) kernel. The sharpen stencil
    // has one neighbor weight (kw[0]) and one center weight (kw[4]):
    //   out = wn * box3x3_sum + (w_center - wn) * center
    const float* kw = kern + ((size_t)c * CHN + c) * 9;
    const float wn = kw[0];
    const float wd = kw[4] - wn;

    const float* xp = x   + (size_t)plane * IMG_H * IMG_W;
    float*       op = out + (size_t)plane * IMG_H * IMG_W;
    const int col = 4 * lane;

    // prime: group 0 input rows sy+1 .. sy+GRP
    vfloat4 A[GRP], B[GRP];
    #pragma unroll
    for (int j = 0; j < GRP; ++j) A[j] = ldrow(xp, sy + 1 + j, col);

    vfloat4 hprev, hcur, ccur;
    if (sy == 0) {
        hprev = (vfloat4){0.f, 0.f, 0.f, 0.f};
    } else {
        hprev = hsum3(*(const vfloat4*)(xp + (size_t)(sy - 1) * IMG_W + col), lane);
    }
    {
        vfloat4 v0 = *(const vfloat4*)(xp + (size_t)sy * IMG_W + col);
        hcur = hsum3(v0, lane);
        ccur = v0;
    }

    #pragma unroll 1
    for (int g = 0; g < NG; g += 2) {
        const int y = sy + g * GRP;

        // prefetch group g+1 while computing group g (ping-pong, no copies)
        #pragma unroll
        for (int j = 0; j < GRP; ++j) B[j] = ldrow(xp, y + GRP + 1 + j, col);
        compute_group(A, hprev, hcur, ccur, wn, wd, op, y, col, lane);

        // prefetch group g+2 while computing group g+1
        if (g + 2 < NG) {
            #pragma unroll
            for (int j = 0; j < GRP; ++j) A[j] = ldrow(xp, y + 2 * GRP + 1 + j, col);
        }
        compute_group(B, hprev, hcur, ccur, wn, wd, op, y + GRP, col, lane);
    }
}

extern "C" void kernel_launch(void* const* d_in, const int* in_sizes, int n_in,
                              void* d_out, int out_size, void* d_ws, size_t ws_size,
                              hipStream_t stream) {
    const float* x    = (const float*)d_in[0];
    const float* kern = (const float*)d_in[1];
    float* out        = (float*)d_out;

    const int n_strips = 16 * CHN * (IMG_H / STRIP);   // 6144 waves = 6/SIMD exactly
    const int grid     = n_strips / WPB;               // 768 blocks

    hipLaunchKernelGGL(sharpen3x3_lean, dim3(grid), dim3(WPB * 64),
                       0, stream, x, kern, out);
}